// Round 4
// baseline (365.691 us; speedup 1.0000x reference)
//
#include <hip/hip_runtime.h>
#include <hip/hip_bf16.h>

typedef __hip_bfloat16 bf16;
typedef unsigned short u16;
typedef __attribute__((ext_vector_type(8))) short bfrag;   // 8 bf16 = 4 VGPR
typedef __attribute__((ext_vector_type(4))) float cfrag;   // 4 f32 acc

union BF { bfrag v; u16 u[8]; unsigned w[4]; };
union CF { cfrag v; float f[4]; };

#define MFMA(a,b,c) __builtin_amdgcn_mfma_f32_16x16x32_bf16(a,b,c,0,0,0)

#define BB   256
#define NN   128
#define IND  9
#define HDD  128
#define LLY  4
#define OUTD 60
#define LOG2E 1.44269504f
#define STR  136                                  // LDS row stride (u16), 16B-multiple

__device__ __forceinline__ float b2f(bf16 v){ return __bfloat162float(v); }
__device__ __forceinline__ float u2f(u16 u){ return __uint_as_float(((unsigned)u) << 16); }
__device__ __forceinline__ u16 f2bf_bits(float f){
    unsigned u = __float_as_uint(f);
    return (u16)((u + 0x7FFFu + ((u >> 16) & 1u)) >> 16);   // RNE
}
__device__ __forceinline__ unsigned pk2(float a, float b){
    union { __hip_bfloat162 h; unsigned u; } c;
    c.h = __float22bfloat162_rn(make_float2(a, b));          // v_cvt_pk_bf16_f32
    return c.u;
}
__device__ __forceinline__ u16 f2bf1(float f){               // 1-instr RNE convert
    return (u16)pk2(f, 0.f);
}
__device__ __forceinline__ float wave_sum(float v){
    #pragma unroll
    for (int m = 32; m; m >>= 1) v += __shfl_xor(v, m, 64);
    return v;
}
__device__ __forceinline__ float ldin(const void* p, int i, bool isbf){
    return isbf ? b2f(((const bf16*)p)[i]) : ((const float*)p)[i];
}

struct SrcPtrs { const void* p[28]; };

// compact f32 param buffer layout (element offsets):
// cw0 cb1152 bg1280 bb1408 bm1536 bv1664 lng1792 lnb2304 fb1:2816 fb2:3840
// ng4352 nb4480 pw4608 pb20992 hw1:21120 hb1:29312 hw2:29376 hb2:33216 end33276
__device__ const int NCV_OFF[19] = {0,1152,1280,1408,1536,1664,1792,2304,2816,3840,
                                    4352,4480,4608,20992,21120,29312,29376,33216,33276};
__device__ const int NCV_SRC[18] = {1,2,3,4,5,6,10,11,13,15,16,17,18,19,20,21,22,23};

// ====== fused prep v2: coalesced LDS-tiled transposes ======
// Round-4: the old k_prep transposed W/ffn_w1/ffn_w2 with stride-512B reads
// (64 cache lines per wave-load) across 1635 blocks — ~80 us of the ~100 us
// dur_us-vs-k_net gap. Now each 128x128 tile is one block: coalesced read ->
// LDS u16[128][130] (pad => conflict-free column read) -> coalesced write.
// blocks: 0..130 pf | 131..134 WT | 135..142 w1T | 143..150 w2T |
//         151..182 WAb | 183..246 ew2 | 247..374 Aw
__global__ __launch_bounds__(256) void k_prep(
    SrcPtrs S, float* __restrict__ pf,
    u16* __restrict__ WT, u16* __restrict__ w1T, u16* __restrict__ w2T,
    u16* __restrict__ WAb, u16* __restrict__ ew2, u16* __restrict__ Aw16,
    int* __restrict__ flagOut)
{
    __shared__ u16 T[128][130];                // +2 pad: u32 row stride 65 (odd) => no bank conflicts
    __shared__ float red[2];

    const unsigned* xw = (const unsigned*)S.p[0];
    int lane = threadIdx.x & 63;
    int cnt = 0;
    for (int i = lane; i < 512; i += 64) {
        float v = __uint_as_float((xw[i] & 0xFFFFu) << 16);
        if (!(fabsf(v) < 32.f)) cnt++;
    }
    bool isbf = wave_sum((float)cnt) < 16.f;
    if (blockIdx.x == 0 && threadIdx.x == 0) *flagOut = isbf ? 1 : 0;

    int blk = blockIdx.x, tid = threadIdx.x;
    if (blk < 131) {                               // small-param f32 convert (coalesced)
        int idx = blk * 256 + tid;
        if (idx < 33276) {
            int y = 17;
            #pragma unroll 1
            for (int t = 1; t < 18; t++) if (idx < NCV_OFF[t]) { y = t - 1; break; }
            pf[idx] = ldin(S.p[NCV_SRC[y]], idx - NCV_OFF[y], isbf);
        }
    } else if (blk < 135) {                        // WT[l][n][k] <- W[l][k][n], 128x128 tile
        int l = blk - 131;
        #pragma unroll 4
        for (int it = 0; it < 64; it++) {
            int idx = it * 256 + tid, k = idx >> 7, n = idx & 127;
            T[k][n] = f2bf_bits(ldin(S.p[7], (l << 14) + k * 128 + n, isbf));
        }
        __syncthreads();
        #pragma unroll 4
        for (int it = 0; it < 64; it++) {
            int idx = it * 256 + tid, n = idx >> 7, k = idx & 127;
            WT[(l << 14) + n * 128 + k] = T[k][n];
        }
    } else if (blk < 143) {                        // w1T[l][n256][k128] <- w1[l][k128][n256], half-tiles
        int q = blk - 135, l = q >> 1, hf = q & 1;
        #pragma unroll 4
        for (int it = 0; it < 64; it++) {
            int idx = it * 256 + tid, k = idx >> 7, nn = idx & 127;
            T[k][nn] = f2bf_bits(ldin(S.p[12], (l << 15) + k * 256 + hf * 128 + nn, isbf));
        }
        __syncthreads();
        #pragma unroll 4
        for (int it = 0; it < 64; it++) {
            int idx = it * 256 + tid, nn = idx >> 7, k = idx & 127;
            w1T[(l << 15) + (hf * 128 + nn) * 128 + k] = T[k][nn];
        }
    } else if (blk < 151) {                        // w2T[l][n128][k256] <- w2[l][k256][n128], k-half tiles
        int q = blk - 143, l = q >> 1, kh = q & 1;
        #pragma unroll 4
        for (int it = 0; it < 64; it++) {
            int idx = it * 256 + tid, kk = idx >> 7, nn = idx & 127;
            T[kk][nn] = f2bf_bits(ldin(S.p[14], (l << 15) + (kh * 128 + kk) * 128 + nn, isbf));
        }
        __syncthreads();
        #pragma unroll 4
        for (int it = 0; it < 64; it++) {
            int idx = it * 256 + tid, n = idx >> 7, kk = idx & 127;
            w2T[(l << 15) + n * 256 + kh * 128 + kk] = T[kk][n];
        }
    } else if (blk < 183) {                        // WAb[l][n16][k128] = (W @ [asrc|adst])^T
        int j = (blk - 151) * 256 + tid;           // 8192
        int l = j >> 11, r = j & 2047, n = r >> 7, k = r & 127;
        int h = n & 7;
        const void* ap = (n < 8) ? S.p[8] : S.p[9];
        float sacc = 0.f;
        #pragma unroll 1
        for (int d = 0; d < 16; d++)
            sacc += ldin(S.p[7], l * 16384 + k * 128 + h * 16 + d, isbf)
                  * ldin(ap, l * 128 + h * 16 + d, isbf);
        WAb[j] = f2bf_bits(sacc);
    } else if (blk < 247) {                        // ew2 = log2e*(mask? ewa : -1e30)
        int j = (blk - 183) * 256 + tid;
        float sav = ldin(S.p[24], j, isbf);
        float ewv = ldin(S.p[27], j, isbf);
        ew2[j] = f2bf_bits(sav > 0.f ? ewv * LOG2E : -1e30f);
    } else {                                       // Aw row-normalized, bf16
        int i = blk - 247, j = tid & 127;
        float v = 0.f;
        if (tid < 128) {
            float wmv = ldin(S.p[25], i * 128 + j, isbf);
            float wpv = ldin(S.p[26], i * 128 + j, isbf);
            v = wmv / (1.f + __expf(-wpv));
            float sm = wave_sum(v);
            if ((tid & 63) == 0) red[tid >> 6] = sm;
        }
        __syncthreads();
        if (tid < 128) {
            float tot = red[0] + red[1];
            Aw16[i * 128 + j] = f2bf_bits(v / (tot + 1e-5f));
        }
    }
}

// ====== whole-network megakernel: 1 block per graph, 512 thr = 8 waves, 16 rows/wave ======
// Round-4: exact revert to the proven round-0 structure (252 us). Occupancy x2,
// ILP x2 and VALU cuts all failed to move it — only the single-instruction bf16
// convert (f2bf1) is kept from rounds 1-3.
// LDS: Abuf = h16A / hid (wave-private rows), Bbuf = hpT / gbuf (hpT cross-wave),
// st2 = s2 f32 [8][128] | t2 bf16 [8][128] | head scratch. 77,824 B total.
#define LDSB (2*128*STR*2 + 8192)
__global__ __launch_bounds__(512, 2) void k_net(
    const void* __restrict__ xraw, const int* __restrict__ flag,
    const float* __restrict__ pf,
    const u16* __restrict__ WTg, const u16* __restrict__ WAbg,
    const u16* __restrict__ Awg, const u16* __restrict__ ew2g,
    const u16* __restrict__ w1Tg, const u16* __restrict__ w2Tg,
    void* __restrict__ outv)
{
    extern __shared__ __align__(16) char smem[];
    u16* Abuf = (u16*)smem;                    // [128][STR] h16A, later hid (per-wave rows)
    u16* Bbuf = Abuf + 128 * STR;              // [128][STR] hpT (cross-wave), later gbuf
    float* st2 = (float*)(Bbuf + 128 * STR);   // 2048 f32
    float* s2  = st2;                          // [8][128] f32
    u16*   t2u = (u16*)(st2 + 1024);           // [8][128] bf16

    const int b = blockIdx.x;
    const int tid = threadIdx.x, lane = tid & 63, wv = tid >> 6;
    const int l15 = lane & 15, kg = lane >> 4;
    const int wrow = wv * 16;
    const bool isbf = (*flag != 0);

    float hreg[8][4];                          // residual h, C-frag layout (own 16 rows)

    // ---------- embed: conv1d + BN + relu, into hreg + Abuf ----------
    {
        float xr[4][9];
        #pragma unroll
        for (int r = 0; r < 4; r++) {
            int bn = b * NN + wrow + kg * 4 + r;
            #pragma unroll
            for (int k = 0; k < IND; k++) xr[r][k] = ldin(xraw, bn * IND + k, isbf);
        }
        #pragma unroll 1
        for (int nt = 0; nt < 8; nt++) {
            int d = nt * 16 + l15;
            float cwreg[IND];
            #pragma unroll
            for (int k = 0; k < IND; k++) cwreg[k] = pf[d * IND + k];
            float scale = rsqrtf(pf[1664 + d] + 1e-5f) * pf[1280 + d];
            float bias  = pf[1408 + d] - pf[1536 + d] * scale;
            float cbd   = pf[1152 + d];
            #pragma unroll
            for (int r = 0; r < 4; r++) {
                float a = cbd;
                #pragma unroll
                for (int k = 0; k < IND; k++) a = fmaf(xr[r][k], cwreg[k], a);
                a = fmaxf(fmaf(a, scale, bias), 0.f);
                hreg[nt][r] = a;
                Abuf[(wrow + kg * 4 + r) * STR + d] = f2bf1(a);
            }
        }
    }

    const int arow = wrow + l15;               // this lane's A-frag row

    // ---------- 4 layers ----------
    #pragma unroll 1
    for (int l = 0; l < LLY; l++) {
        const u16* WT  = WTg  + l * 16384;
        const u16* WAb = WAbg + l * 2048;
        const u16* w1T = w1Tg + l * 32768;
        const u16* w2T = w2Tg + l * 32768;
        const float* fb1 = pf + 2816 + l * 256;
        const float* fb2 = pf + 3840 + l * 128;
        const float* lng = pf + 1792 + l * 128;
        const float* lnb = pf + 2304 + l * 128;

        __syncthreads();                       // Bbuf free: prior-layer gbuf readers done

        // P1: hp = h @ W (own 16 rows) + s,t = h @ (W·a)
        {
            CF acc[8], ast;
            #pragma unroll
            for (int r = 0; r < 4; r++) ast.f[r] = 0.f;
            #pragma unroll
            for (int nt = 0; nt < 8; nt++)
                #pragma unroll
                for (int r = 0; r < 4; r++) acc[nt].f[r] = 0.f;
            #pragma unroll 1
            for (int kk = 0; kk < 4; kk++) {
                bfrag af  = *(const bfrag*)&Abuf[arow * STR + kk*32 + kg*8];
                bfrag wab = *(const bfrag*)&WAb[l15 * 128 + kk*32 + kg*8];
                ast.v = MFMA(af, wab, ast.v);
                #pragma unroll
                for (int nt = 0; nt < 8; nt++) {
                    bfrag bw = *(const bfrag*)&WT[(nt*16 + l15) * 128 + kk*32 + kg*8];
                    acc[nt].v = MFMA(af, bw, acc[nt].v);
                }
            }
            #pragma unroll
            for (int nt = 0; nt < 8; nt++) {
                int col = nt*16 + l15;
                #pragma unroll
                for (int rp = 0; rp < 2; rp++) {
                    int row = wrow + kg*4 + rp*2;
                    *(unsigned*)&Bbuf[col * STR + row] = pk2(acc[nt].f[rp*2], acc[nt].f[rp*2+1]);
                }
            }
            #pragma unroll
            for (int r = 0; r < 4; r++) {      // s (cols 0-7) f32, t (cols 8-15) bf16
                int node = wrow + kg*4 + r;
                float v = ast.f[r] * LOG2E;
                if (l15 < 8) s2[l15 * 128 + node] = v;
                else         t2u[(l15 - 8) * 128 + node] = f2bf1(v);
            }
        }
        __syncthreads();                       // hpT, s2, t2 ready

        // P2: weak = Aw @ hp
        CF accW[8];
        #pragma unroll
        for (int nt = 0; nt < 8; nt++)
            #pragma unroll
            for (int r = 0; r < 4; r++) accW[nt].f[r] = 0.f;
        #pragma unroll 1
        for (int kk = 0; kk < 4; kk++) {
            bfrag awf = *(const bfrag*)&Awg[arow * 128 + kk*32 + kg*8];
            #pragma unroll
            for (int nt = 0; nt < 8; nt++) {
                bfrag hb2 = *(const bfrag*)&Bbuf[(nt*16 + l15) * STR + kk*32 + kg*8];
                accW[nt].v = MFMA(awf, hb2, accW[nt].v);
            }
        }

        // P3: softmax (exp2, no max-sub) + strong MFMA
        CF accS[8];
        #pragma unroll
        for (int nt = 0; nt < 8; nt++)
            #pragma unroll
            for (int r = 0; r < 4; r++) accS[nt].f[r] = 0.f;
        #pragma unroll 1
        for (int h = 0; h < 8; h++) {
            bfrag hb[4];
            #pragma unroll
            for (int kk = 0; kk < 4; kk++)
                hb[kk] = *(const bfrag*)&Bbuf[(h*16 + l15) * STR + kk*32 + kg*8];
            float sA = s2[h * 128 + arow];
            float pv[4][8];
            float sm = 0.f;
            #pragma unroll
            for (int kk = 0; kk < 4; kk++) {
                BF tb; tb.v = *(const bfrag*)&t2u[h * 128 + kk*32 + kg*8];
                BF e2; e2.v = *(const bfrag*)&ew2g[arow * 128 + kk*32 + kg*8];
                #pragma unroll
                for (int j = 0; j < 8; j++) {
                    float x2 = sA + u2f(tb.u[j]);
                    float lk = fmaxf(x2, 0.2f * x2);                 // log2e*leaky(s+t)
                    float p = __builtin_amdgcn_exp2f(lk + u2f(e2.u[j]));  // masked -> 0
                    pv[kk][j] = p; sm += p;
                }
            }
            sm += __shfl_xor(sm, 16, 64);
            sm += __shfl_xor(sm, 32, 64);
            float inv = __builtin_amdgcn_rcpf(sm);
            #pragma unroll
            for (int kk = 0; kk < 4; kk++) {
                BF pb;
                #pragma unroll
                for (int q = 0; q < 4; q++)
                    pb.w[q] = pk2(pv[kk][2*q] * inv, pv[kk][2*q+1] * inv);
                accS[h].v = MFMA(pb.v, hb[kk], accS[h].v);
            }
        }
        __syncthreads();                       // all hpT reads done -> Bbuf reusable as gbuf

        // P4: g = relu(0.6 s + 0.4 w) + LN -> gbuf (own rows; no barrier needed after)
        {
            float gv[8][4];
            #pragma unroll
            for (int nt = 0; nt < 8; nt++)
                #pragma unroll
                for (int r = 0; r < 4; r++)
                    gv[nt][r] = fmaxf(0.6f * accS[nt].f[r] + 0.4f * accW[nt].f[r], 0.f);
            #pragma unroll
            for (int r = 0; r < 4; r++) {
                float s1 = 0.f, sq = 0.f;
                #pragma unroll
                for (int nt = 0; nt < 8; nt++) { float x = gv[nt][r]; s1 += x; sq = fmaf(x, x, sq); }
                #pragma unroll
                for (int m = 1; m <= 8; m <<= 1) { s1 += __shfl_xor(s1, m, 64); sq += __shfl_xor(sq, m, 64); }
                float mu = s1 * (1.f / 128.f);
                float var = sq * (1.f / 128.f) - mu * mu;
                float rs = rsqrtf(fmaxf(var, 0.f) + 1e-5f);
                #pragma unroll
                for (int nt = 0; nt < 8; nt++) {
                    int col = nt*16 + l15;
                    Bbuf[(wrow + kg*4 + r) * STR + col] =
                        f2bf1(fmaf((gv[nt][r] - mu) * rs, lng[col], lnb[col]));
                }
            }
        }

        // P5: FFN, two N-halves; gbuf/hid are wave-private rows -> no barriers
        CF acc2[8];
        #pragma unroll
        for (int nt = 0; nt < 8; nt++)
            #pragma unroll
            for (int r = 0; r < 4; r++) acc2[nt].f[r] = 0.f;
        #pragma unroll 1
        for (int nh = 0; nh < 2; nh++) {
            CF a1[8];
            #pragma unroll
            for (int nt = 0; nt < 8; nt++)
                #pragma unroll
                for (int r = 0; r < 4; r++) a1[nt].f[r] = 0.f;
            #pragma unroll 1
            for (int kk = 0; kk < 4; kk++) {
                bfrag gf = *(const bfrag*)&Bbuf[arow * STR + kk*32 + kg*8];
                #pragma unroll
                for (int nt = 0; nt < 8; nt++) {
                    bfrag wf = *(const bfrag*)&w1T[(nh*128 + nt*16 + l15) * 128 + kk*32 + kg*8];
                    a1[nt].v = MFMA(gf, wf, a1[nt].v);
                }
            }
            #pragma unroll
            for (int nt = 0; nt < 8; nt++) {
                int col = nt*16 + l15;
                float b1v = fb1[nh*128 + col];
                #pragma unroll
                for (int r = 0; r < 4; r++)
                    Abuf[(wrow + kg*4 + r) * STR + col] = f2bf1(fmaxf(a1[nt].f[r] + b1v, 0.f));
            }
            #pragma unroll 1
            for (int kk = 0; kk < 4; kk++) {
                bfrag hf = *(const bfrag*)&Abuf[arow * STR + kk*32 + kg*8];
                #pragma unroll
                for (int nt = 0; nt < 8; nt++) {
                    bfrag wf = *(const bfrag*)&w2T[(nt*16 + l15) * 256 + nh*128 + kk*32 + kg*8];
                    acc2[nt].v = MFMA(hf, wf, acc2[nt].v);
                }
            }
        }

        // epilogue: residual in regs; rebuild h16A (own rows) for next layer
        #pragma unroll
        for (int nt = 0; nt < 8; nt++) {
            float b2v = fb2[nt*16 + l15];
            #pragma unroll
            for (int r = 0; r < 4; r++) hreg[nt][r] += acc2[nt].f[r] + b2v;
        }
        if (l < LLY - 1) {
            #pragma unroll
            for (int nt = 0; nt < 8; nt++) {
                int col = nt*16 + l15;
                #pragma unroll
                for (int r = 0; r < 4; r++)
                    Abuf[(wrow + kg*4 + r) * STR + col] = f2bf1(hreg[nt][r]);
            }
        }
    }

    // ---------- final LN + node-sum (proj commutes with mean) ----------
    const float* ng = pf + 4352;
    const float* nb = pf + 4480;
    float pacc[8];
    #pragma unroll
    for (int nt = 0; nt < 8; nt++) pacc[nt] = 0.f;
    #pragma unroll
    for (int r = 0; r < 4; r++) {
        float s1 = 0.f, sq = 0.f;
        #pragma unroll
        for (int nt = 0; nt < 8; nt++) { float x = hreg[nt][r]; s1 += x; sq = fmaf(x, x, sq); }
        #pragma unroll
        for (int m = 1; m <= 8; m <<= 1) { s1 += __shfl_xor(s1, m, 64); sq += __shfl_xor(sq, m, 64); }
        float mu = s1 * (1.f / 128.f);
        float var = sq * (1.f / 128.f) - mu * mu;
        float rs = rsqrtf(fmaxf(var, 0.f) + 1e-5f);
        #pragma unroll
        for (int nt = 0; nt < 8; nt++) {
            int col = nt*16 + l15;
            pacc[nt] += fmaf((hreg[nt][r] - mu) * rs, ng[col], nb[col]);
        }
    }
    #pragma unroll
    for (int nt = 0; nt < 8; nt++) {           // sum across kg groups (rows of this wave)
        pacc[nt] += __shfl_xor(pacc[nt], 16, 64);
        pacc[nt] += __shfl_xor(pacc[nt], 32, 64);
    }
    __syncthreads();                           // st2 free (last t2/s2 reads were pre-barrier2)
    if (kg == 0) {
        #pragma unroll
        for (int nt = 0; nt < 8; nt++) st2[wv * 128 + nt*16 + l15] = pacc[nt];
    }
    __syncthreads();
    // pooled mean -> st2[1024..1152)
    if (tid < 128) {
        float tot = 0.f;
        #pragma unroll
        for (int w = 0; w < 8; w++) tot += st2[w * 128 + tid];
        st2[1024 + tid] = tot * (1.f / 128.f);
    }
    __syncthreads();
    // proj: 4 k-quarters x 128 cols -> st2[1152..1664)
    {
        int e = tid & 127, kq = tid >> 7;
        float a = 0.f;
        #pragma unroll 4
        for (int k = kq * 32; k < kq * 32 + 32; k++)
            a = fmaf(st2[1024 + k], pf[4608 + k * 128 + e], a);
        st2[1152 + kq * 128 + e] = a;
    }
    __syncthreads();
    if (tid < 128)
        st2[1664 + tid] = st2[1152 + tid] + st2[1280 + tid] + st2[1408 + tid] + st2[1536 + tid]
                        + pf[20992 + tid];
    __syncthreads();
    if (tid < 64) {
        float a1 = pf[29312 + tid];
        #pragma unroll 4
        for (int k = 0; k < 128; k++) a1 = fmaf(st2[1664 + k], pf[21120 + k * 64 + tid], a1);
        st2[1792 + tid] = fmaxf(a1, 0.f);
    }
    __syncthreads();
    if (tid < OUTD) {
        float a2 = pf[33216 + tid];
        #pragma unroll 4
        for (int k = 0; k < 64; k++) a2 = fmaf(st2[1792 + k], pf[29376 + k * OUTD + tid], a2);
        if (isbf) ((bf16*)outv)[b * OUTD + tid] = __float2bfloat16(a2);
        else      ((float*)outv)[b * OUTD + tid] = a2;
    }
}

extern "C" void kernel_launch(void* const* d_in, const int* in_sizes, int n_in,
                              void* d_out, int out_size, void* d_ws, size_t ws_size,
                              hipStream_t stream)
{
    float* ws = (float*)d_ws;
    float* pf = ws;                                // compact f32 params [0..33276)
    int*   flag = (int*)(ws + 33280);
    u16* WT16   = (u16*)(ws + 33536);              // 65,536
    u16* w1T16  = WT16 + 65536;                    // 131,072
    u16* w2T16  = w1T16 + 131072;                  // 131,072
    u16* WAb16  = w2T16 + 131072;                  // 8,192
    u16* Aw16   = WAb16 + 8192;                    // 16,384
    u16* ew2p   = Aw16 + 16384;                    // 16,384

    SrcPtrs S;
    for (int i = 0; i < 28; i++) S.p[i] = d_in[i];

    hipFuncSetAttribute((const void*)k_net,
                        hipFuncAttributeMaxDynamicSharedMemorySize, LDSB);

    k_prep<<<375, 256, 0, stream>>>(S, pf, WT16, w1T16, w2T16, WAb16, ew2p, Aw16, flag);
    k_net<<<BB, 512, LDSB, stream>>>(d_in[0], flag, pf,
                                     WT16, WAb16, Aw16, ew2p, w1T16, w2T16, d_out);
}

// Round 5
// 350.168 us; speedup vs baseline: 1.0443x; 1.0443x over previous
//
#include <hip/hip_runtime.h>
#include <hip/hip_bf16.h>

typedef __hip_bfloat16 bf16;
typedef unsigned short u16;
typedef __attribute__((ext_vector_type(8))) short bfrag;   // 8 bf16 = 4 VGPR
typedef __attribute__((ext_vector_type(4))) float cfrag;   // 4 f32 acc
typedef __attribute__((ext_vector_type(2))) float f32x2;   // packed f32 pair -> v_pk_*_f32

union BF { bfrag v; u16 u[8]; unsigned w[4]; };
union CF { cfrag v; float f[4]; };

#define MFMA(a,b,c) __builtin_amdgcn_mfma_f32_16x16x32_bf16(a,b,c,0,0,0)

#define BB   256
#define NN   128
#define IND  9
#define HDD  128
#define LLY  4
#define OUTD 60
#define LOG2E 1.44269504f
#define STR  136                                  // LDS row stride (u16), 16B-multiple

__device__ __forceinline__ float b2f(bf16 v){ return __bfloat162float(v); }
__device__ __forceinline__ float u2f(u16 u){ return __uint_as_float(((unsigned)u) << 16); }
__device__ __forceinline__ u16 f2bf_bits(float f){
    unsigned u = __float_as_uint(f);
    return (u16)((u + 0x7FFFu + ((u >> 16) & 1u)) >> 16);   // RNE
}
__device__ __forceinline__ unsigned pk2(float a, float b){
    union { __hip_bfloat162 h; unsigned u; } c;
    c.h = __float22bfloat162_rn(make_float2(a, b));          // v_cvt_pk_bf16_f32
    return c.u;
}
__device__ __forceinline__ u16 f2bf1(float f){               // 1-instr RNE convert
    return (u16)pk2(f, 0.f);
}
__device__ __forceinline__ float wave_sum(float v){
    #pragma unroll
    for (int m = 32; m; m >>= 1) v += __shfl_xor(v, m, 64);
    return v;
}
__device__ __forceinline__ float ldin(const void* p, int i, bool isbf){
    return isbf ? b2f(((const bf16*)p)[i]) : ((const float*)p)[i];
}

struct SrcPtrs { const void* p[28]; };

// compact f32 param buffer layout (element offsets):
// cw0 cb1152 bg1280 bb1408 bm1536 bv1664 lng1792 lnb2304 fb1:2816 fb2:3840
// ng4352 nb4480 pw4608 pb20992 hw1:21120 hb1:29312 hw2:29376 hb2:33216 end33276
__device__ const int NCV_OFF[19] = {0,1152,1280,1408,1536,1664,1792,2304,2816,3840,
                                    4352,4480,4608,20992,21120,29312,29376,33216,33276};
__device__ const int NCV_SRC[18] = {1,2,3,4,5,6,10,11,13,15,16,17,18,19,20,21,22,23};

// ====== fused prep: round-0 version verbatim (1635 blocks). The r4 "coalesced"
// tiled rewrite was ~13 us SLOWER end-to-end: 20 blocks x 64 serial latency-chain
// iterations lost more to serialization than coalescing gained. Massive block
// count hides the uncoalesced latency better. ======
__global__ __launch_bounds__(256) void k_prep(
    SrcPtrs S, float* __restrict__ pf,
    u16* __restrict__ WT, u16* __restrict__ w1T, u16* __restrict__ w2T,
    u16* __restrict__ WAb, u16* __restrict__ ew2, u16* __restrict__ Aw16,
    int* __restrict__ flagOut)
{
    const unsigned* xw = (const unsigned*)S.p[0];
    int lane = threadIdx.x & 63;
    int cnt = 0;
    for (int i = lane; i < 512; i += 64) {
        float v = __uint_as_float((xw[i] & 0xFFFFu) << 16);
        if (!(fabsf(v) < 32.f)) cnt++;
    }
    bool isbf = wave_sum((float)cnt) < 16.f;
    if (blockIdx.x == 0 && threadIdx.x == 0) *flagOut = isbf ? 1 : 0;

    int blk = blockIdx.x, tid = threadIdx.x;
    if (blk < 131) {                               // small-param f32 convert
        int idx = blk * 256 + tid;
        if (idx < 33276) {
            int y = 17;
            #pragma unroll 1
            for (int t = 1; t < 18; t++) if (idx < NCV_OFF[t]) { y = t - 1; break; }
            pf[idx] = ldin(S.p[NCV_SRC[y]], idx - NCV_OFF[y], isbf);
        }
    } else if (blk < 387) {                        // WT[l][n128][k128] <- W[l][k][n]
        int j = (blk - 131) * 256 + tid;
        int l = j >> 14, r = j & 16383, n = r >> 7, k = r & 127;
        WT[j] = f2bf_bits(ldin(S.p[7], (l << 14) + k * 128 + n, isbf));
    } else if (blk < 899) {                        // w1T[l][n256][k128]
        int j = (blk - 387) * 256 + tid;
        int l = j >> 15, r = j & 32767, n = r >> 7, k = r & 127;
        w1T[j] = f2bf_bits(ldin(S.p[12], (l << 15) + k * 256 + n, isbf));
    } else if (blk < 1411) {                       // w2T[l][n128][k256]
        int j = (blk - 899) * 256 + tid;
        int l = j >> 15, r = j & 32767, n = r >> 8, k = r & 255;
        w2T[j] = f2bf_bits(ldin(S.p[14], (l << 15) + k * 128 + n, isbf));
    } else if (blk < 1443) {                       // WAb[l][n16][k128] = (W @ [asrc|adst])^T
        int j = (blk - 1411) * 256 + tid;          // 8192
        int l = j >> 11, r = j & 2047, n = r >> 7, k = r & 127;
        int h = n & 7;
        const void* ap = (n < 8) ? S.p[8] : S.p[9];
        float sacc = 0.f;
        #pragma unroll 1
        for (int d = 0; d < 16; d++)
            sacc += ldin(S.p[7], l * 16384 + k * 128 + h * 16 + d, isbf)
                  * ldin(ap, l * 128 + h * 16 + d, isbf);
        WAb[j] = f2bf_bits(sacc);
    } else if (blk < 1507) {                       // ew2 = log2e*(mask? ewa : -1e30)
        int j = (blk - 1443) * 256 + tid;
        float sav = ldin(S.p[24], j, isbf);
        float ewv = ldin(S.p[27], j, isbf);
        ew2[j] = f2bf_bits(sav > 0.f ? ewv * LOG2E : -1e30f);
    } else {                                       // Aw row-normalized, bf16
        __shared__ float red[2];
        int i = blk - 1507, j = tid & 127;
        float v = 0.f;
        if (tid < 128) {
            float wmv = ldin(S.p[25], i * 128 + j, isbf);
            float wpv = ldin(S.p[26], i * 128 + j, isbf);
            v = wmv / (1.f + __expf(-wpv));
            float sm = wave_sum(v);
            if ((tid & 63) == 0) red[tid >> 6] = sm;
        }
        __syncthreads();
        if (tid < 128) {
            float tot = red[0] + red[1];
            Aw16[i * 128 + j] = f2bf_bits(v / (tot + 1e-5f));
        }
    }
}

// ====== whole-network megakernel: 1 block per graph, 512 thr = 8 waves, 16 rows/wave ======
// Round-5: round-0 schedule untouched (3 barriers/layer, unroll-1 kk loops, P2->P3
// order, pre-normalized P3). Only schedule-neutral VALU cuts: f2bf1 converts,
// ew2 hoisted+preconverted once per layer (was 8x), packed f32x2 exp-arg chain.
// LDS: Abuf = h16A / hid (wave-private rows), Bbuf = hpT / gbuf (hpT cross-wave),
// st2 = s2 f32 [8][128] | t2 bf16 [8][128] | head scratch. 77,824 B total.
#define LDSB (2*128*STR*2 + 8192)
__global__ __launch_bounds__(512, 2) void k_net(
    const void* __restrict__ xraw, const int* __restrict__ flag,
    const float* __restrict__ pf,
    const u16* __restrict__ WTg, const u16* __restrict__ WAbg,
    const u16* __restrict__ Awg, const u16* __restrict__ ew2g,
    const u16* __restrict__ w1Tg, const u16* __restrict__ w2Tg,
    void* __restrict__ outv)
{
    extern __shared__ __align__(16) char smem[];
    u16* Abuf = (u16*)smem;                    // [128][STR] h16A, later hid (per-wave rows)
    u16* Bbuf = Abuf + 128 * STR;              // [128][STR] hpT (cross-wave), later gbuf
    float* st2 = (float*)(Bbuf + 128 * STR);   // 2048 f32
    float* s2  = st2;                          // [8][128] f32
    u16*   t2u = (u16*)(st2 + 1024);           // [8][128] bf16

    const int b = blockIdx.x;
    const int tid = threadIdx.x, lane = tid & 63, wv = tid >> 6;
    const int l15 = lane & 15, kg = lane >> 4;
    const int wrow = wv * 16;
    const bool isbf = (*flag != 0);

    float hreg[8][4];                          // residual h, C-frag layout (own 16 rows)

    // ---------- embed: conv1d + BN + relu, into hreg + Abuf ----------
    {
        float xr[4][9];
        #pragma unroll
        for (int r = 0; r < 4; r++) {
            int bn = b * NN + wrow + kg * 4 + r;
            #pragma unroll
            for (int k = 0; k < IND; k++) xr[r][k] = ldin(xraw, bn * IND + k, isbf);
        }
        #pragma unroll 1
        for (int nt = 0; nt < 8; nt++) {
            int d = nt * 16 + l15;
            float cwreg[IND];
            #pragma unroll
            for (int k = 0; k < IND; k++) cwreg[k] = pf[d * IND + k];
            float scale = rsqrtf(pf[1664 + d] + 1e-5f) * pf[1280 + d];
            float bias  = pf[1408 + d] - pf[1536 + d] * scale;
            float cbd   = pf[1152 + d];
            #pragma unroll
            for (int r = 0; r < 4; r++) {
                float a = cbd;
                #pragma unroll
                for (int k = 0; k < IND; k++) a = fmaf(xr[r][k], cwreg[k], a);
                a = fmaxf(fmaf(a, scale, bias), 0.f);
                hreg[nt][r] = a;
                Abuf[(wrow + kg * 4 + r) * STR + d] = f2bf1(a);
            }
        }
    }

    const int arow = wrow + l15;               // this lane's A-frag row

    // ---------- 4 layers ----------
    #pragma unroll 1
    for (int l = 0; l < LLY; l++) {
        const u16* WT  = WTg  + l * 16384;
        const u16* WAb = WAbg + l * 2048;
        const u16* w1T = w1Tg + l * 32768;
        const u16* w2T = w2Tg + l * 32768;
        const float* fb1 = pf + 2816 + l * 256;
        const float* fb2 = pf + 3840 + l * 128;
        const float* lng = pf + 1792 + l * 128;
        const float* lnb = pf + 2304 + l * 128;

        __syncthreads();                       // Bbuf free: prior-layer gbuf readers done

        // P1: hp = h @ W (own 16 rows) + s,t = h @ (W·a)
        {
            CF acc[8], ast;
            #pragma unroll
            for (int r = 0; r < 4; r++) ast.f[r] = 0.f;
            #pragma unroll
            for (int nt = 0; nt < 8; nt++)
                #pragma unroll
                for (int r = 0; r < 4; r++) acc[nt].f[r] = 0.f;
            #pragma unroll 1
            for (int kk = 0; kk < 4; kk++) {
                bfrag af  = *(const bfrag*)&Abuf[arow * STR + kk*32 + kg*8];
                bfrag wab = *(const bfrag*)&WAb[l15 * 128 + kk*32 + kg*8];
                ast.v = MFMA(af, wab, ast.v);
                #pragma unroll
                for (int nt = 0; nt < 8; nt++) {
                    bfrag bw = *(const bfrag*)&WT[(nt*16 + l15) * 128 + kk*32 + kg*8];
                    acc[nt].v = MFMA(af, bw, acc[nt].v);
                }
            }
            #pragma unroll
            for (int nt = 0; nt < 8; nt++) {
                int col = nt*16 + l15;
                #pragma unroll
                for (int rp = 0; rp < 2; rp++) {
                    int row = wrow + kg*4 + rp*2;
                    *(unsigned*)&Bbuf[col * STR + row] = pk2(acc[nt].f[rp*2], acc[nt].f[rp*2+1]);
                }
            }
            #pragma unroll
            for (int r = 0; r < 4; r++) {      // s (cols 0-7) f32, t (cols 8-15) bf16
                int node = wrow + kg*4 + r;
                float v = ast.f[r] * LOG2E;
                if (l15 < 8) s2[l15 * 128 + node] = v;
                else         t2u[(l15 - 8) * 128 + node] = f2bf1(v);
            }
        }
        __syncthreads();                       // hpT, s2, t2 ready

        // P2: weak = Aw @ hp
        CF accW[8];
        #pragma unroll
        for (int nt = 0; nt < 8; nt++)
            #pragma unroll
            for (int r = 0; r < 4; r++) accW[nt].f[r] = 0.f;
        #pragma unroll 1
        for (int kk = 0; kk < 4; kk++) {
            bfrag awf = *(const bfrag*)&Awg[arow * 128 + kk*32 + kg*8];
            #pragma unroll
            for (int nt = 0; nt < 8; nt++) {
                bfrag hb2 = *(const bfrag*)&Bbuf[(nt*16 + l15) * STR + kk*32 + kg*8];
                accW[nt].v = MFMA(awf, hb2, accW[nt].v);
            }
        }

        // P3: softmax (exp2, no max-sub) + strong MFMA. ew2 hoisted (was re-loaded
        // and re-converted 8x per layer); exp-arg chain in packed f32x2.
        CF accS[8];
        #pragma unroll
        for (int nt = 0; nt < 8; nt++)
            #pragma unroll
            for (int r = 0; r < 4; r++) accS[nt].f[r] = 0.f;
        {
            f32x2 e2f[4][4];                   // head-invariant masked edge bias
            #pragma unroll
            for (int kk = 0; kk < 4; kk++) {
                BF e2; e2.v = *(const bfrag*)&ew2g[arow * 128 + kk*32 + kg*8];
                #pragma unroll
                for (int q = 0; q < 4; q++) {
                    unsigned w = e2.w[q];
                    e2f[kk][q].x = __uint_as_float(w << 16);
                    e2f[kk][q].y = __uint_as_float(w & 0xffff0000u);
                }
            }
            #pragma unroll 1
            for (int h = 0; h < 8; h++) {
                bfrag hb[4];
                #pragma unroll
                for (int kk = 0; kk < 4; kk++)
                    hb[kk] = *(const bfrag*)&Bbuf[(h*16 + l15) * STR + kk*32 + kg*8];
                float sA = s2[h * 128 + arow];
                f32x2 sA2; sA2.x = sA; sA2.y = sA;
                f32x2 pv[4][4];
                float sm = 0.f;
                #pragma unroll
                for (int kk = 0; kk < 4; kk++) {
                    BF tb; tb.v = *(const bfrag*)&t2u[h * 128 + kk*32 + kg*8];
                    #pragma unroll
                    for (int q = 0; q < 4; q++) {
                        unsigned w = tb.w[q];
                        f32x2 tv;
                        tv.x = __uint_as_float(w << 16);
                        tv.y = __uint_as_float(w & 0xffff0000u);
                        f32x2 x2 = sA2 + tv;                           // v_pk_add_f32
                        f32x2 lk = __builtin_elementwise_max(x2, x2 * 0.2f); // pk_mul+pk_max
                        f32x2 ex = lk + e2f[kk][q];                    // v_pk_add_f32
                        float p0 = __builtin_amdgcn_exp2f(ex.x);       // masked -> 0
                        float p1 = __builtin_amdgcn_exp2f(ex.y);
                        pv[kk][q].x = p0; pv[kk][q].y = p1;
                        sm += p0 + p1;
                    }
                }
                sm += __shfl_xor(sm, 16, 64);
                sm += __shfl_xor(sm, 32, 64);
                float inv = __builtin_amdgcn_rcpf(sm);
                #pragma unroll
                for (int kk = 0; kk < 4; kk++) {
                    BF pb;
                    #pragma unroll
                    for (int q = 0; q < 4; q++) {
                        f32x2 pn = pv[kk][q] * inv;                    // v_pk_mul_f32
                        pb.w[q] = pk2(pn.x, pn.y);
                    }
                    accS[h].v = MFMA(pb.v, hb[kk], accS[h].v);
                }
            }
        }
        __syncthreads();                       // all hpT reads done -> Bbuf reusable as gbuf

        // P4: g = relu(0.6 s + 0.4 w) + LN -> gbuf (own rows; no barrier needed after)
        {
            float gv[8][4];
            #pragma unroll
            for (int nt = 0; nt < 8; nt++)
                #pragma unroll
                for (int r = 0; r < 4; r++)
                    gv[nt][r] = fmaxf(0.6f * accS[nt].f[r] + 0.4f * accW[nt].f[r], 0.f);
            #pragma unroll
            for (int r = 0; r < 4; r++) {
                float s1 = 0.f, sq = 0.f;
                #pragma unroll
                for (int nt = 0; nt < 8; nt++) { float x = gv[nt][r]; s1 += x; sq = fmaf(x, x, sq); }
                #pragma unroll
                for (int m = 1; m <= 8; m <<= 1) { s1 += __shfl_xor(s1, m, 64); sq += __shfl_xor(sq, m, 64); }
                float mu = s1 * (1.f / 128.f);
                float var = sq * (1.f / 128.f) - mu * mu;
                float rs = rsqrtf(fmaxf(var, 0.f) + 1e-5f);
                #pragma unroll
                for (int nt = 0; nt < 8; nt++) {
                    int col = nt*16 + l15;
                    Bbuf[(wrow + kg*4 + r) * STR + col] =
                        f2bf1(fmaf((gv[nt][r] - mu) * rs, lng[col], lnb[col]));
                }
            }
        }

        // P5: FFN, two N-halves; gbuf/hid are wave-private rows -> no barriers
        CF acc2[8];
        #pragma unroll
        for (int nt = 0; nt < 8; nt++)
            #pragma unroll
            for (int r = 0; r < 4; r++) acc2[nt].f[r] = 0.f;
        #pragma unroll 1
        for (int nh = 0; nh < 2; nh++) {
            CF a1[8];
            #pragma unroll
            for (int nt = 0; nt < 8; nt++)
                #pragma unroll
                for (int r = 0; r < 4; r++) a1[nt].f[r] = 0.f;
            #pragma unroll 1
            for (int kk = 0; kk < 4; kk++) {
                bfrag gf = *(const bfrag*)&Bbuf[arow * STR + kk*32 + kg*8];
                #pragma unroll
                for (int nt = 0; nt < 8; nt++) {
                    bfrag wf = *(const bfrag*)&w1T[(nh*128 + nt*16 + l15) * 128 + kk*32 + kg*8];
                    a1[nt].v = MFMA(gf, wf, a1[nt].v);
                }
            }
            #pragma unroll
            for (int nt = 0; nt < 8; nt++) {
                int col = nt*16 + l15;
                float b1v = fb1[nh*128 + col];
                #pragma unroll
                for (int r = 0; r < 4; r++)
                    Abuf[(wrow + kg*4 + r) * STR + col] = f2bf1(fmaxf(a1[nt].f[r] + b1v, 0.f));
            }
            #pragma unroll 1
            for (int kk = 0; kk < 4; kk++) {
                bfrag hf = *(const bfrag*)&Abuf[arow * STR + kk*32 + kg*8];
                #pragma unroll
                for (int nt = 0; nt < 8; nt++) {
                    bfrag wf = *(const bfrag*)&w2T[(nt*16 + l15) * 256 + nh*128 + kk*32 + kg*8];
                    acc2[nt].v = MFMA(hf, wf, acc2[nt].v);
                }
            }
        }

        // epilogue: residual in regs; rebuild h16A (own rows) for next layer
        #pragma unroll
        for (int nt = 0; nt < 8; nt++) {
            float b2v = fb2[nt*16 + l15];
            #pragma unroll
            for (int r = 0; r < 4; r++) hreg[nt][r] += acc2[nt].f[r] + b2v;
        }
        if (l < LLY - 1) {
            #pragma unroll
            for (int nt = 0; nt < 8; nt++) {
                int col = nt*16 + l15;
                #pragma unroll
                for (int r = 0; r < 4; r++)
                    Abuf[(wrow + kg*4 + r) * STR + col] = f2bf1(hreg[nt][r]);
            }
        }
    }

    // ---------- final LN + node-sum (proj commutes with mean) ----------
    const float* ng = pf + 4352;
    const float* nb = pf + 4480;
    float pacc[8];
    #pragma unroll
    for (int nt = 0; nt < 8; nt++) pacc[nt] = 0.f;
    #pragma unroll
    for (int r = 0; r < 4; r++) {
        float s1 = 0.f, sq = 0.f;
        #pragma unroll
        for (int nt = 0; nt < 8; nt++) { float x = hreg[nt][r]; s1 += x; sq = fmaf(x, x, sq); }
        #pragma unroll
        for (int m = 1; m <= 8; m <<= 1) { s1 += __shfl_xor(s1, m, 64); sq += __shfl_xor(sq, m, 64); }
        float mu = s1 * (1.f / 128.f);
        float var = sq * (1.f / 128.f) - mu * mu;
        float rs = rsqrtf(fmaxf(var, 0.f) + 1e-5f);
        #pragma unroll
        for (int nt = 0; nt < 8; nt++) {
            int col = nt*16 + l15;
            pacc[nt] += fmaf((hreg[nt][r] - mu) * rs, ng[col], nb[col]);
        }
    }
    #pragma unroll
    for (int nt = 0; nt < 8; nt++) {           // sum across kg groups (rows of this wave)
        pacc[nt] += __shfl_xor(pacc[nt], 16, 64);
        pacc[nt] += __shfl_xor(pacc[nt], 32, 64);
    }
    __syncthreads();                           // st2 free (last t2/s2 reads were pre-barrier2)
    if (kg == 0) {
        #pragma unroll
        for (int nt = 0; nt < 8; nt++) st2[wv * 128 + nt*16 + l15] = pacc[nt];
    }
    __syncthreads();
    // pooled mean -> st2[1024..1152)
    if (tid < 128) {
        float tot = 0.f;
        #pragma unroll
        for (int w = 0; w < 8; w++) tot += st2[w * 128 + tid];
        st2[1024 + tid] = tot * (1.f / 128.f);
    }
    __syncthreads();
    // proj: 4 k-quarters x 128 cols -> st2[1152..1664)
    {
        int e = tid & 127, kq = tid >> 7;
        float a = 0.f;
        #pragma unroll 4
        for (int k = kq * 32; k < kq * 32 + 32; k++)
            a = fmaf(st2[1024 + k], pf[4608 + k * 128 + e], a);
        st2[1152 + kq * 128 + e] = a;
    }
    __syncthreads();
    if (tid < 128)
        st2[1664 + tid] = st2[1152 + tid] + st2[1280 + tid] + st2[1408 + tid] + st2[1536 + tid]
                        + pf[20992 + tid];
    __syncthreads();
    if (tid < 64) {
        float a1 = pf[29312 + tid];
        #pragma unroll 4
        for (int k = 0; k < 128; k++) a1 = fmaf(st2[1664 + k], pf[21120 + k * 64 + tid], a1);
        st2[1792 + tid] = fmaxf(a1, 0.f);
    }
    __syncthreads();
    if (tid < OUTD) {
        float a2 = pf[33216 + tid];
        #pragma unroll 4
        for (int k = 0; k < 64; k++) a2 = fmaf(st2[1792 + k], pf[29376 + k * OUTD + tid], a2);
        if (isbf) ((bf16*)outv)[b * OUTD + tid] = __float2bfloat16(a2);
        else      ((float*)outv)[b * OUTD + tid] = a2;
    }
}

extern "C" void kernel_launch(void* const* d_in, const int* in_sizes, int n_in,
                              void* d_out, int out_size, void* d_ws, size_t ws_size,
                              hipStream_t stream)
{
    float* ws = (float*)d_ws;
    float* pf = ws;                                // compact f32 params [0..33276)
    int*   flag = (int*)(ws + 33280);
    u16* WT16   = (u16*)(ws + 33536);              // 65,536
    u16* w1T16  = WT16 + 65536;                    // 131,072
    u16* w2T16  = w1T16 + 131072;                  // 131,072
    u16* WAb16  = w2T16 + 131072;                  // 8,192
    u16* Aw16   = WAb16 + 8192;                    // 16,384
    u16* ew2p   = Aw16 + 16384;                    // 16,384

    SrcPtrs S;
    for (int i = 0; i < 28; i++) S.p[i] = d_in[i];

    hipFuncSetAttribute((const void*)k_net,
                        hipFuncAttributeMaxDynamicSharedMemorySize, LDSB);

    k_prep<<<1635, 256, 0, stream>>>(S, pf, WT16, w1T16, w2T16, WAb16, ew2p, Aw16, flag);
    k_net<<<BB, 512, LDSB, stream>>>(d_in[0], flag, pf,
                                     WT16, WAb16, Aw16, ew2p, w1T16, w2T16, d_out);
}

// Round 6
// 340.884 us; speedup vs baseline: 1.0728x; 1.0272x over previous
//
#include <hip/hip_runtime.h>
#include <hip/hip_bf16.h>

typedef __hip_bfloat16 bf16;
typedef unsigned short u16;
typedef __attribute__((ext_vector_type(8))) short bfrag;   // 8 bf16 = 4 VGPR
typedef __attribute__((ext_vector_type(4))) float cfrag;   // 4 f32 acc
typedef __attribute__((ext_vector_type(2))) float f32x2;   // packed f32 pair -> v_pk_*_f32

union BF { bfrag v; u16 u[8]; unsigned w[4]; };
union CF { cfrag v; float f[4]; };

#define MFMA(a,b,c) __builtin_amdgcn_mfma_f32_16x16x32_bf16(a,b,c,0,0,0)

#define BB   256
#define NN   128
#define IND  9
#define HDD  128
#define LLY  4
#define OUTD 60
#define LOG2E 1.44269504f
#define STR  136                                  // LDS row stride (u16), 16B-multiple

__device__ __forceinline__ float b2f(bf16 v){ return __bfloat162float(v); }
__device__ __forceinline__ float u2f(u16 u){ return __uint_as_float(((unsigned)u) << 16); }
__device__ __forceinline__ u16 f2bf_bits(float f){
    unsigned u = __float_as_uint(f);
    return (u16)((u + 0x7FFFu + ((u >> 16) & 1u)) >> 16);   // RNE
}
__device__ __forceinline__ unsigned pk2(float a, float b){
    union { __hip_bfloat162 h; unsigned u; } c;
    c.h = __float22bfloat162_rn(make_float2(a, b));          // v_cvt_pk_bf16_f32
    return c.u;
}
__device__ __forceinline__ u16 f2bf1(float f){               // 1-instr RNE convert
    return (u16)pk2(f, 0.f);
}
__device__ __forceinline__ float wave_sum(float v){
    #pragma unroll
    for (int m = 32; m; m >>= 1) v += __shfl_xor(v, m, 64);
    return v;
}
__device__ __forceinline__ float ldin(const void* p, int i, bool isbf){
    return isbf ? b2f(((const bf16*)p)[i]) : ((const float*)p)[i];
}

struct SrcPtrs { const void* p[28]; };

// compact f32 param buffer layout (element offsets):
// cw0 cb1152 bg1280 bb1408 bm1536 bv1664 lng1792 lnb2304 fb1:2816 fb2:3840
// ng4352 nb4480 pw4608 pb20992 hw1:21120 hb1:29312 hw2:29376 hb2:33216 end33276
__device__ const int NCV_OFF[19] = {0,1152,1280,1408,1536,1664,1792,2304,2816,3840,
                                    4352,4480,4608,20992,21120,29312,29376,33216,33276};
__device__ const int NCV_SRC[18] = {1,2,3,4,5,6,10,11,13,15,16,17,18,19,20,21,22,23};

// ====== fused prep: round-0 version verbatim (1635 blocks). ======
__global__ __launch_bounds__(256) void k_prep(
    SrcPtrs S, float* __restrict__ pf,
    u16* __restrict__ WT, u16* __restrict__ w1T, u16* __restrict__ w2T,
    u16* __restrict__ WAb, u16* __restrict__ ew2, u16* __restrict__ Aw16,
    int* __restrict__ flagOut)
{
    const unsigned* xw = (const unsigned*)S.p[0];
    int lane = threadIdx.x & 63;
    int cnt = 0;
    for (int i = lane; i < 512; i += 64) {
        float v = __uint_as_float((xw[i] & 0xFFFFu) << 16);
        if (!(fabsf(v) < 32.f)) cnt++;
    }
    bool isbf = wave_sum((float)cnt) < 16.f;
    if (blockIdx.x == 0 && threadIdx.x == 0) *flagOut = isbf ? 1 : 0;

    int blk = blockIdx.x, tid = threadIdx.x;
    if (blk < 131) {                               // small-param f32 convert
        int idx = blk * 256 + tid;
        if (idx < 33276) {
            int y = 17;
            #pragma unroll 1
            for (int t = 1; t < 18; t++) if (idx < NCV_OFF[t]) { y = t - 1; break; }
            pf[idx] = ldin(S.p[NCV_SRC[y]], idx - NCV_OFF[y], isbf);
        }
    } else if (blk < 387) {                        // WT[l][n128][k128] <- W[l][k][n]
        int j = (blk - 131) * 256 + tid;
        int l = j >> 14, r = j & 16383, n = r >> 7, k = r & 127;
        WT[j] = f2bf_bits(ldin(S.p[7], (l << 14) + k * 128 + n, isbf));
    } else if (blk < 899) {                        // w1T[l][n256][k128]
        int j = (blk - 387) * 256 + tid;
        int l = j >> 15, r = j & 32767, n = r >> 7, k = r & 127;
        w1T[j] = f2bf_bits(ldin(S.p[12], (l << 15) + k * 256 + n, isbf));
    } else if (blk < 1411) {                       // w2T[l][n128][k256]
        int j = (blk - 899) * 256 + tid;
        int l = j >> 15, r = j & 32767, n = r >> 8, k = r & 255;
        w2T[j] = f2bf_bits(ldin(S.p[14], (l << 15) + k * 128 + n, isbf));
    } else if (blk < 1443) {                       // WAb[l][n16][k128] = (W @ [asrc|adst])^T
        int j = (blk - 1411) * 256 + tid;          // 8192
        int l = j >> 11, r = j & 2047, n = r >> 7, k = r & 127;
        int h = n & 7;
        const void* ap = (n < 8) ? S.p[8] : S.p[9];
        float sacc = 0.f;
        #pragma unroll 1
        for (int d = 0; d < 16; d++)
            sacc += ldin(S.p[7], l * 16384 + k * 128 + h * 16 + d, isbf)
                  * ldin(ap, l * 128 + h * 16 + d, isbf);
        WAb[j] = f2bf_bits(sacc);
    } else if (blk < 1507) {                       // ew2 = log2e*(mask? ewa : -1e30)
        int j = (blk - 1443) * 256 + tid;
        float sav = ldin(S.p[24], j, isbf);
        float ewv = ldin(S.p[27], j, isbf);
        ew2[j] = f2bf_bits(sav > 0.f ? ewv * LOG2E : -1e30f);
    } else {                                       // Aw row-normalized, bf16
        __shared__ float red[2];
        int i = blk - 1507, j = tid & 127;
        float v = 0.f;
        if (tid < 128) {
            float wmv = ldin(S.p[25], i * 128 + j, isbf);
            float wpv = ldin(S.p[26], i * 128 + j, isbf);
            v = wmv / (1.f + __expf(-wpv));
            float sm = wave_sum(v);
            if ((tid & 63) == 0) red[tid >> 6] = sm;
        }
        __syncthreads();
        if (tid < 128) {
            float tot = red[0] + red[1];
            Aw16[i * 128 + j] = f2bf_bits(v / (tot + 1e-5f));
        }
    }
}

// ====== whole-network megakernel: 1 block per graph, 512 thr = 8 waves, 16 rows/wave ======
// Round-6: de-scratch the register state (guide rule #20). r0-r5 had two
// runtime-indexed register arrays forcing scratch allocation (the 53.7 MB/dispatch
// HBM WRITE_SIZE signature): hreg (embed's unroll-1 nt loop) and accS (P3's
// runtime h index). Fix: fully unroll embed; P3 accumulates into a local CF t and
// stores via a wave-uniform switch(h) so every accS access is constant-indexed.
// Schedule is otherwise byte-identical to r5 (r0 barriers/order + VALU cuts).
#define LDSB (2*128*STR*2 + 8192)
__global__ __launch_bounds__(512, 2) void k_net(
    const void* __restrict__ xraw, const int* __restrict__ flag,
    const float* __restrict__ pf,
    const u16* __restrict__ WTg, const u16* __restrict__ WAbg,
    const u16* __restrict__ Awg, const u16* __restrict__ ew2g,
    const u16* __restrict__ w1Tg, const u16* __restrict__ w2Tg,
    void* __restrict__ outv)
{
    extern __shared__ __align__(16) char smem[];
    u16* Abuf = (u16*)smem;                    // [128][STR] h16A, later hid (per-wave rows)
    u16* Bbuf = Abuf + 128 * STR;              // [128][STR] hpT (cross-wave), later gbuf
    float* st2 = (float*)(Bbuf + 128 * STR);   // 2048 f32
    float* s2  = st2;                          // [8][128] f32
    u16*   t2u = (u16*)(st2 + 1024);           // [8][128] bf16

    const int b = blockIdx.x;
    const int tid = threadIdx.x, lane = tid & 63, wv = tid >> 6;
    const int l15 = lane & 15, kg = lane >> 4;
    const int wrow = wv * 16;
    const bool isbf = (*flag != 0);

    float hreg[8][4];                          // residual h — ALL accesses static => VGPRs

    // ---------- embed: conv1d + BN + relu, into hreg + Abuf (fully unrolled) ----------
    {
        float xr[4][9];
        #pragma unroll
        for (int r = 0; r < 4; r++) {
            int bn = b * NN + wrow + kg * 4 + r;
            #pragma unroll
            for (int k = 0; k < IND; k++) xr[r][k] = ldin(xraw, bn * IND + k, isbf);
        }
        #pragma unroll
        for (int nt = 0; nt < 8; nt++) {
            int d = nt * 16 + l15;
            float cwreg[IND];
            #pragma unroll
            for (int k = 0; k < IND; k++) cwreg[k] = pf[d * IND + k];
            float scale = rsqrtf(pf[1664 + d] + 1e-5f) * pf[1280 + d];
            float bias  = pf[1408 + d] - pf[1536 + d] * scale;
            float cbd   = pf[1152 + d];
            #pragma unroll
            for (int r = 0; r < 4; r++) {
                float a = cbd;
                #pragma unroll
                for (int k = 0; k < IND; k++) a = fmaf(xr[r][k], cwreg[k], a);
                a = fmaxf(fmaf(a, scale, bias), 0.f);
                hreg[nt][r] = a;
                Abuf[(wrow + kg * 4 + r) * STR + d] = f2bf1(a);
            }
        }
    }

    const int arow = wrow + l15;               // this lane's A-frag row

    // ---------- 4 layers ----------
    #pragma unroll 1
    for (int l = 0; l < LLY; l++) {
        const u16* WT  = WTg  + l * 16384;
        const u16* WAb = WAbg + l * 2048;
        const u16* w1T = w1Tg + l * 32768;
        const u16* w2T = w2Tg + l * 32768;
        const float* fb1 = pf + 2816 + l * 256;
        const float* fb2 = pf + 3840 + l * 128;
        const float* lng = pf + 1792 + l * 128;
        const float* lnb = pf + 2304 + l * 128;

        __syncthreads();                       // Bbuf free: prior-layer gbuf readers done

        // P1: hp = h @ W (own 16 rows) + s,t = h @ (W·a)
        {
            CF acc[8], ast;
            #pragma unroll
            for (int r = 0; r < 4; r++) ast.f[r] = 0.f;
            #pragma unroll
            for (int nt = 0; nt < 8; nt++)
                #pragma unroll
                for (int r = 0; r < 4; r++) acc[nt].f[r] = 0.f;
            #pragma unroll 1
            for (int kk = 0; kk < 4; kk++) {
                bfrag af  = *(const bfrag*)&Abuf[arow * STR + kk*32 + kg*8];
                bfrag wab = *(const bfrag*)&WAb[l15 * 128 + kk*32 + kg*8];
                ast.v = MFMA(af, wab, ast.v);
                #pragma unroll
                for (int nt = 0; nt < 8; nt++) {
                    bfrag bw = *(const bfrag*)&WT[(nt*16 + l15) * 128 + kk*32 + kg*8];
                    acc[nt].v = MFMA(af, bw, acc[nt].v);
                }
            }
            #pragma unroll
            for (int nt = 0; nt < 8; nt++) {
                int col = nt*16 + l15;
                #pragma unroll
                for (int rp = 0; rp < 2; rp++) {
                    int row = wrow + kg*4 + rp*2;
                    *(unsigned*)&Bbuf[col * STR + row] = pk2(acc[nt].f[rp*2], acc[nt].f[rp*2+1]);
                }
            }
            #pragma unroll
            for (int r = 0; r < 4; r++) {      // s (cols 0-7) f32, t (cols 8-15) bf16
                int node = wrow + kg*4 + r;
                float v = ast.f[r] * LOG2E;
                if (l15 < 8) s2[l15 * 128 + node] = v;
                else         t2u[(l15 - 8) * 128 + node] = f2bf1(v);
            }
        }
        __syncthreads();                       // hpT, s2, t2 ready

        // P2: weak = Aw @ hp
        CF accW[8];
        #pragma unroll
        for (int nt = 0; nt < 8; nt++)
            #pragma unroll
            for (int r = 0; r < 4; r++) accW[nt].f[r] = 0.f;
        #pragma unroll 1
        for (int kk = 0; kk < 4; kk++) {
            bfrag awf = *(const bfrag*)&Awg[arow * 128 + kk*32 + kg*8];
            #pragma unroll
            for (int nt = 0; nt < 8; nt++) {
                bfrag hb2 = *(const bfrag*)&Bbuf[(nt*16 + l15) * STR + kk*32 + kg*8];
                accW[nt].v = MFMA(awf, hb2, accW[nt].v);
            }
        }

        // P3: softmax (exp2, no max-sub) + strong MFMA. Local accumulator t (static),
        // switch(h) store => accS stays in VGPRs (h loop stays rolled for code size).
        CF accS[8];
        {
            f32x2 e2f[4][4];                   // head-invariant masked edge bias
            #pragma unroll
            for (int kk = 0; kk < 4; kk++) {
                BF e2; e2.v = *(const bfrag*)&ew2g[arow * 128 + kk*32 + kg*8];
                #pragma unroll
                for (int q = 0; q < 4; q++) {
                    unsigned w = e2.w[q];
                    e2f[kk][q].x = __uint_as_float(w << 16);
                    e2f[kk][q].y = __uint_as_float(w & 0xffff0000u);
                }
            }
            #pragma unroll 1
            for (int h = 0; h < 8; h++) {
                bfrag hb[4];
                #pragma unroll
                for (int kk = 0; kk < 4; kk++)
                    hb[kk] = *(const bfrag*)&Bbuf[(h*16 + l15) * STR + kk*32 + kg*8];
                float sA = s2[h * 128 + arow];
                f32x2 sA2; sA2.x = sA; sA2.y = sA;
                f32x2 pv[4][4];
                float sm = 0.f;
                #pragma unroll
                for (int kk = 0; kk < 4; kk++) {
                    BF tb; tb.v = *(const bfrag*)&t2u[h * 128 + kk*32 + kg*8];
                    #pragma unroll
                    for (int q = 0; q < 4; q++) {
                        unsigned w = tb.w[q];
                        f32x2 tv;
                        tv.x = __uint_as_float(w << 16);
                        tv.y = __uint_as_float(w & 0xffff0000u);
                        f32x2 x2 = sA2 + tv;                           // v_pk_add_f32
                        f32x2 lk = __builtin_elementwise_max(x2, x2 * 0.2f); // pk_mul+pk_max
                        f32x2 ex = lk + e2f[kk][q];                    // v_pk_add_f32
                        float p0 = __builtin_amdgcn_exp2f(ex.x);       // masked -> 0
                        float p1 = __builtin_amdgcn_exp2f(ex.y);
                        pv[kk][q].x = p0; pv[kk][q].y = p1;
                        sm += p0 + p1;
                    }
                }
                sm += __shfl_xor(sm, 16, 64);
                sm += __shfl_xor(sm, 32, 64);
                float inv = __builtin_amdgcn_rcpf(sm);
                CF t;
                #pragma unroll
                for (int r = 0; r < 4; r++) t.f[r] = 0.f;
                #pragma unroll
                for (int kk = 0; kk < 4; kk++) {
                    BF pb;
                    #pragma unroll
                    for (int q = 0; q < 4; q++) {
                        f32x2 pn = pv[kk][q] * inv;                    // v_pk_mul_f32
                        pb.w[q] = pk2(pn.x, pn.y);
                    }
                    t.v = MFMA(pb.v, hb[kk], t.v);
                }
                switch (h) {                   // wave-uniform; constant-indexed stores
                    case 0: accS[0] = t; break;
                    case 1: accS[1] = t; break;
                    case 2: accS[2] = t; break;
                    case 3: accS[3] = t; break;
                    case 4: accS[4] = t; break;
                    case 5: accS[5] = t; break;
                    case 6: accS[6] = t; break;
                    case 7: accS[7] = t; break;
                }
            }
        }
        __syncthreads();                       // all hpT reads done -> Bbuf reusable as gbuf

        // P4: g = relu(0.6 s + 0.4 w) + LN -> gbuf (own rows; no barrier needed after)
        {
            float gv[8][4];
            #pragma unroll
            for (int nt = 0; nt < 8; nt++)
                #pragma unroll
                for (int r = 0; r < 4; r++)
                    gv[nt][r] = fmaxf(0.6f * accS[nt].f[r] + 0.4f * accW[nt].f[r], 0.f);
            #pragma unroll
            for (int r = 0; r < 4; r++) {
                float s1 = 0.f, sq = 0.f;
                #pragma unroll
                for (int nt = 0; nt < 8; nt++) { float x = gv[nt][r]; s1 += x; sq = fmaf(x, x, sq); }
                #pragma unroll
                for (int m = 1; m <= 8; m <<= 1) { s1 += __shfl_xor(s1, m, 64); sq += __shfl_xor(sq, m, 64); }
                float mu = s1 * (1.f / 128.f);
                float var = sq * (1.f / 128.f) - mu * mu;
                float rs = rsqrtf(fmaxf(var, 0.f) + 1e-5f);
                #pragma unroll
                for (int nt = 0; nt < 8; nt++) {
                    int col = nt*16 + l15;
                    Bbuf[(wrow + kg*4 + r) * STR + col] =
                        f2bf1(fmaf((gv[nt][r] - mu) * rs, lng[col], lnb[col]));
                }
            }
        }

        // P5: FFN, two N-halves; gbuf/hid are wave-private rows -> no barriers
        CF acc2[8];
        #pragma unroll
        for (int nt = 0; nt < 8; nt++)
            #pragma unroll
            for (int r = 0; r < 4; r++) acc2[nt].f[r] = 0.f;
        #pragma unroll 1
        for (int nh = 0; nh < 2; nh++) {
            CF a1[8];
            #pragma unroll
            for (int nt = 0; nt < 8; nt++)
                #pragma unroll
                for (int r = 0; r < 4; r++) a1[nt].f[r] = 0.f;
            #pragma unroll 1
            for (int kk = 0; kk < 4; kk++) {
                bfrag gf = *(const bfrag*)&Bbuf[arow * STR + kk*32 + kg*8];
                #pragma unroll
                for (int nt = 0; nt < 8; nt++) {
                    bfrag wf = *(const bfrag*)&w1T[(nh*128 + nt*16 + l15) * 128 + kk*32 + kg*8];
                    a1[nt].v = MFMA(gf, wf, a1[nt].v);
                }
            }
            #pragma unroll
            for (int nt = 0; nt < 8; nt++) {
                int col = nt*16 + l15;
                float b1v = fb1[nh*128 + col];
                #pragma unroll
                for (int r = 0; r < 4; r++)
                    Abuf[(wrow + kg*4 + r) * STR + col] = f2bf1(fmaxf(a1[nt].f[r] + b1v, 0.f));
            }
            #pragma unroll 1
            for (int kk = 0; kk < 4; kk++) {
                bfrag hf = *(const bfrag*)&Abuf[arow * STR + kk*32 + kg*8];
                #pragma unroll
                for (int nt = 0; nt < 8; nt++) {
                    bfrag wf = *(const bfrag*)&w2T[(nt*16 + l15) * 256 + nh*128 + kk*32 + kg*8];
                    acc2[nt].v = MFMA(hf, wf, acc2[nt].v);
                }
            }
        }

        // epilogue: residual in regs; rebuild h16A (own rows) for next layer
        #pragma unroll
        for (int nt = 0; nt < 8; nt++) {
            float b2v = fb2[nt*16 + l15];
            #pragma unroll
            for (int r = 0; r < 4; r++) hreg[nt][r] += acc2[nt].f[r] + b2v;
        }
        if (l < LLY - 1) {
            #pragma unroll
            for (int nt = 0; nt < 8; nt++) {
                int col = nt*16 + l15;
                #pragma unroll
                for (int r = 0; r < 4; r++)
                    Abuf[(wrow + kg*4 + r) * STR + col] = f2bf1(hreg[nt][r]);
            }
        }
    }

    // ---------- final LN + node-sum (proj commutes with mean) ----------
    const float* ng = pf + 4352;
    const float* nb = pf + 4480;
    float pacc[8];
    #pragma unroll
    for (int nt = 0; nt < 8; nt++) pacc[nt] = 0.f;
    #pragma unroll
    for (int r = 0; r < 4; r++) {
        float s1 = 0.f, sq = 0.f;
        #pragma unroll
        for (int nt = 0; nt < 8; nt++) { float x = hreg[nt][r]; s1 += x; sq = fmaf(x, x, sq); }
        #pragma unroll
        for (int m = 1; m <= 8; m <<= 1) { s1 += __shfl_xor(s1, m, 64); sq += __shfl_xor(sq, m, 64); }
        float mu = s1 * (1.f / 128.f);
        float var = sq * (1.f / 128.f) - mu * mu;
        float rs = rsqrtf(fmaxf(var, 0.f) + 1e-5f);
        #pragma unroll
        for (int nt = 0; nt < 8; nt++) {
            int col = nt*16 + l15;
            pacc[nt] += fmaf((hreg[nt][r] - mu) * rs, ng[col], nb[col]);
        }
    }
    #pragma unroll
    for (int nt = 0; nt < 8; nt++) {           // sum across kg groups (rows of this wave)
        pacc[nt] += __shfl_xor(pacc[nt], 16, 64);
        pacc[nt] += __shfl_xor(pacc[nt], 32, 64);
    }
    __syncthreads();                           // st2 free (last t2/s2 reads were pre-barrier2)
    if (kg == 0) {
        #pragma unroll
        for (int nt = 0; nt < 8; nt++) st2[wv * 128 + nt*16 + l15] = pacc[nt];
    }
    __syncthreads();
    // pooled mean -> st2[1024..1152)
    if (tid < 128) {
        float tot = 0.f;
        #pragma unroll
        for (int w = 0; w < 8; w++) tot += st2[w * 128 + tid];
        st2[1024 + tid] = tot * (1.f / 128.f);
    }
    __syncthreads();
    // proj: 4 k-quarters x 128 cols -> st2[1152..1664)
    {
        int e = tid & 127, kq = tid >> 7;
        float a = 0.f;
        #pragma unroll 4
        for (int k = kq * 32; k < kq * 32 + 32; k++)
            a = fmaf(st2[1024 + k], pf[4608 + k * 128 + e], a);
        st2[1152 + kq * 128 + e] = a;
    }
    __syncthreads();
    if (tid < 128)
        st2[1664 + tid] = st2[1152 + tid] + st2[1280 + tid] + st2[1408 + tid] + st2[1536 + tid]
                        + pf[20992 + tid];
    __syncthreads();
    if (tid < 64) {
        float a1 = pf[29312 + tid];
        #pragma unroll 4
        for (int k = 0; k < 128; k++) a1 = fmaf(st2[1664 + k], pf[21120 + k * 64 + tid], a1);
        st2[1792 + tid] = fmaxf(a1, 0.f);
    }
    __syncthreads();
    if (tid < OUTD) {
        float a2 = pf[33216 + tid];
        #pragma unroll 4
        for (int k = 0; k < 64; k++) a2 = fmaf(st2[1792 + k], pf[29376 + k * OUTD + tid], a2);
        if (isbf) ((bf16*)outv)[b * OUTD + tid] = __float2bfloat16(a2);
        else      ((float*)outv)[b * OUTD + tid] = a2;
    }
}

extern "C" void kernel_launch(void* const* d_in, const int* in_sizes, int n_in,
                              void* d_out, int out_size, void* d_ws, size_t ws_size,
                              hipStream_t stream)
{
    float* ws = (float*)d_ws;
    float* pf = ws;                                // compact f32 params [0..33276)
    int*   flag = (int*)(ws + 33280);
    u16* WT16   = (u16*)(ws + 33536);              // 65,536
    u16* w1T16  = WT16 + 65536;                    // 131,072
    u16* w2T16  = w1T16 + 131072;                  // 131,072
    u16* WAb16  = w2T16 + 131072;                  // 8,192
    u16* Aw16   = WAb16 + 8192;                    // 16,384
    u16* ew2p   = Aw16 + 16384;                    // 16,384

    SrcPtrs S;
    for (int i = 0; i < 28; i++) S.p[i] = d_in[i];

    hipFuncSetAttribute((const void*)k_net,
                        hipFuncAttributeMaxDynamicSharedMemorySize, LDSB);

    k_prep<<<1635, 256, 0, stream>>>(S, pf, WT16, w1T16, w2T16, WAb16, ew2p, Aw16, flag);
    k_net<<<BB, 512, LDSB, stream>>>(d_in[0], flag, pf,
                                     WT16, WAb16, Aw16, ew2p, w1T16, w2T16, d_out);
}